// Round 10
// baseline (3563.021 us; speedup 1.0000x reference)
//
#include <hip/hip_runtime.h>

// ODE-GRU on MI355X, round 10.
// Round-9 structure, but 4-way element split: 512 blocks x 1024 threads.
// Thread t: element j=t>>2, quarter p2=t&3 (GRU/stage2); stage1 split 16-way
// (i1=t>>4, k16=t&15). Doubles waves/CU 16->32 (if VGPR<=64) and halves the
// per-thread dot chain -- attacks the latency-bound regime of r9 (VALUBusy
// 45% at 16 waves/CU). Drift weights now 4 named h8 = 16 VGPRs.
// Reductions: DPP xor1(0xB1)/xor2(0x4E)/mirror8(0x141)/mirror16(0x140).
// All LDS patterns interleaved -> <=2-way bank aliases (free per m136).
// Spill tripwire: WRITE_SIZE must stay ~1.6e5 KB.

#define SEQ   256
#define BATCH 512
#define DIN   54
#define HDIM  256
#define DH    64

typedef _Float16 h2 __attribute__((ext_vector_type(2)));
typedef _Float16 h8 __attribute__((ext_vector_type(8)));

#define PX(v, p) __builtin_shufflevector((v), (v), 2*(p), 2*(p)+1)

#if defined(__has_builtin)
#  if __has_builtin(__builtin_amdgcn_fdot2)
#    define FDOT2(a, b, c) __builtin_amdgcn_fdot2((a), (b), (c), false)
#  endif
#endif
#ifndef FDOT2
#  define FDOT2(a, b, c) fmaf((float)(a)[0], (float)(b)[0], \
                         fmaf((float)(a)[1], (float)(b)[1], (c)))
#endif

__device__ __forceinline__ float rcp_f(float x) { return __builtin_amdgcn_rcpf(x); }

__device__ __forceinline__ float fast_tanh(float x) {
    x = fminf(15.0f, fmaxf(-15.0f, x));
    float e = __expf(2.0f * x);
    return 1.0f - 2.0f * rcp_f(e + 1.0f);
}
__device__ __forceinline__ float fast_sigmoid(float x) {
    x = fminf(30.0f, fmaxf(-30.0f, x));
    return rcp_f(1.0f + __expf(-x));
}

// x + dpp_permute(x): cross-lane add at VALU latency.
// 0xB1 quad_perm lane^1; 0x4E quad_perm lane^2; 0x141 row_half_mirror
// (8-lane finisher once quad-uniform); 0x140 row_mirror (16-lane finisher
// once 8-uniform).
template <int CTRL>
__device__ __forceinline__ float dppadd(float x) {
    return x + __int_as_float(
        __builtin_amdgcn_mov_dpp(__float_as_int(x), CTRL, 0xF, 0xF, true));
}

// 4 dot2: accumulate h8 W . h8 Y into A
#define DOT8(A, W, Y) { \
    A = FDOT2(PX(W,0), PX(Y,0), A); A = FDOT2(PX(W,1), PX(Y,1), A); \
    A = FDOT2(PX(W,2), PX(Y,2), A); A = FDOT2(PX(W,3), PX(Y,3), A); }

// Drift eval. Stage1: 16-lane group (i1=t>>4) covers interleaved chunks
// {k16*8, k16*8+128}; lanes 8 apart share banks (2-way, free); DPP
// xor1/xor2/mirror8/mirror16 completes the 256-dot; all lanes get u.
// Stage2: quarter p2 covers u[p2*16..+16) (4 distinct 16B lines/wave,
// conflict-free broadcast); DPP xor1/xor2 completes. 2 barriers.
#define DRIFT(Y_EXPR, KOUT) do {                                              \
    if (p2 == 0) yh[j] = (_Float16)(Y_EXPR);                                  \
    __syncthreads();                                                          \
    float a0_ = 0.f, a1_ = 0.f;                                               \
    {                                                                         \
        h8 v0_ = *(const h8*)(yh + k16 * 8);                                  \
        h8 v1_ = *(const h8*)(yh + k16 * 8 + 128);                            \
        DOT8(a0_, w1a, v0_) DOT8(a1_, w1b, v1_)                               \
    }                                                                         \
    float as_ = a0_ + a1_;                                                    \
    as_ = dppadd<0xB1>(as_);                                                  \
    as_ = dppadd<0x4E>(as_);                                                  \
    as_ = dppadd<0x141>(as_);                                                 \
    as_ = dppadd<0x140>(as_);                                                 \
    float uu_ = fast_tanh(as_ + b1r);                                         \
    if (k16 == 0) uh[i1] = (_Float16)uu_;                                     \
    __syncthreads();                                                          \
    float c0_ = 0.f, c1_ = 0.f;                                               \
    {                                                                         \
        h8 u0_ = *(const h8*)(uh + p2 * 16);                                  \
        h8 u1_ = *(const h8*)(uh + p2 * 16 + 8);                              \
        DOT8(c0_, w2a, u0_) DOT8(c1_, w2b, u1_)                               \
    }                                                                         \
    float cs_ = c0_ + c1_;                                                    \
    cs_ = dppadd<0xB1>(cs_);                                                  \
    cs_ = dppadd<0x4E>(cs_);                                                  \
    KOUT = cs_ + b2r;                                                         \
} while (0)

// ---- prep: f16 GRU weights, [gate][chunk][thread] coalesced for t=0..1023 --
// WHx: 24576 h8. id = g*8192 + q*1024 + t ; W_hh[j+256g][p2*8+q*32 ..+8]
// WIx:  6144 h8. id = g*2048 + q*1024 + t ; W_ih[j+256g][p2*8+q*32 ..+8]
//                (cols >= 54 zero-padded); j=t>>2, p2=t&3.
__global__ __launch_bounds__(256)
void prep_kernel(const float* __restrict__ W_ih, const float* __restrict__ W_hh,
                 h8* __restrict__ WHx, h8* __restrict__ WIx)
{
    const int id = blockIdx.x * 256 + threadIdx.x;
    if (id < 24576) {
        const int g = id >> 13, rem = id & 8191;
        const int q = rem >> 10, t = rem & 1023;
        const int j = t >> 2, p2 = t & 3;
        const float* src = W_hh + (size_t)(j + 256 * g) * HDIM + p2 * 8 + q * 32;
        h8 v;
        #pragma unroll
        for (int e = 0; e < 8; ++e) v[e] = (_Float16)src[e];
        WHx[id] = v;
    } else if (id < 24576 + 6144) {
        const int id2 = id - 24576;
        const int g = id2 >> 11, rem = id2 & 2047;
        const int q = rem >> 10, t = rem & 1023;
        const int j = t >> 2, p2 = t & 3;
        h8 v;
        #pragma unroll
        for (int e = 0; e < 8; ++e) {
            const int col = p2 * 8 + q * 32 + e;
            v[e] = (col < DIN) ? (_Float16)W_ih[(size_t)(j + 256 * g) * DIN + col]
                               : (_Float16)0.0f;
        }
        WIx[id2] = v;
    }
}

__global__ void
__attribute__((amdgpu_flat_work_group_size(1024, 1024), amdgpu_waves_per_eu(4, 8)))
odegru_kernel(const float* __restrict__ x,
              const float* __restrict__ tvec,
              const float* __restrict__ b_ih,
              const float* __restrict__ b_hh,
              const float* __restrict__ W1,
              const float* __restrict__ b1,
              const float* __restrict__ W2,
              const float* __restrict__ b2,
              const h8* __restrict__ WHx,
              const h8* __restrict__ WIx,
              float* __restrict__ out)
{
    const int t   = threadIdx.x;    // 0..1023
    const int b   = blockIdx.x;     // batch row
    const int j   = t >> 2;         // element 0..255
    const int p2  = t & 3;          // quarter
    const int i1  = t >> 4;         // drift stage1 output 0..63
    const int k16 = t & 15;         // stage1 k-chunk

    __shared__ __align__(16) _Float16 yh[HDIM];
    __shared__ __align__(16) _Float16 uh[DH];
    __shared__ __align__(16) _Float16 xh[64];

    // Drift weights -> 4 named h8 vars (16 VGPRs).
    // w1a/b: W1[i1][k16*8], W1[i1][k16*8+128] ; w2a/b: W2[j][p2*16 (+8)]
    h8 w1a, w1b, w2a, w2b;
    {
        const float* base = W1 + (size_t)i1 * HDIM + k16 * 8;
        h8 v;
        #pragma unroll
        for (int e = 0; e < 8; ++e) v[e] = (_Float16)base[e];       w1a = v;
        #pragma unroll
        for (int e = 0; e < 8; ++e) v[e] = (_Float16)base[e + 128]; w1b = v;
    }
    {
        const float* base = W2 + (size_t)j * DH + p2 * 16;
        h8 v;
        #pragma unroll
        for (int e = 0; e < 8; ++e) v[e] = (_Float16)base[e];       w2a = v;
        #pragma unroll
        for (int e = 0; e < 8; ++e) v[e] = (_Float16)base[e + 8];   w2b = v;
    }

    const float b1r  = b1[i1];
    const float b2r  = b2[j];
    const float bihr = b_ih[j], bihz = b_ih[j + HDIM], bihn = b_ih[j + 2 * HDIM];
    const float bhhr = b_hh[j], bhhz = b_hh[j + HDIM], bhhn = b_hh[j + 2 * HDIM];

    float h = 0.0f;

    for (int i = 0; i < SEQ; ++i) {
        const int s = SEQ - 1 - i;

        if (t < 64)
            xh[t] = (t < DIN) ? (_Float16)x[((size_t)s * BATCH + b) * DIN + t]
                              : (_Float16)0.0f;
        if (p2 == 0) yh[j] = (_Float16)h;
        __syncthreads();

        // ---- GRU: quarter-split dots, f32 accumulate ----
        float xr = 0.f, xz = 0.f, xn = 0.f;                 // ih partials
        #pragma unroll
        for (int q = 0; q < 2; ++q) {
            h8 xv = *(const h8*)(xh + p2 * 8 + q * 32);
            h8 wr = WIx[(0 * 2 + q) * 1024 + t];
            h8 wz = WIx[(1 * 2 + q) * 1024 + t];
            h8 wn = WIx[(2 * 2 + q) * 1024 + t];
            DOT8(xr, wr, xv) DOT8(xz, wz, xv) DOT8(xn, wn, xv)
        }
        float hr0 = 0.f, hz0 = 0.f, hn0 = 0.f;              // hh partials
        float hr1 = 0.f, hz1 = 0.f, hn1 = 0.f;
        #pragma unroll 2
        for (int q = 0; q < 8; q += 2) {
            {
                h8 yv = *(const h8*)(yh + p2 * 8 + q * 32);
                h8 wr = WHx[(0 * 8 + q) * 1024 + t];
                h8 wz = WHx[(1 * 8 + q) * 1024 + t];
                h8 wn = WHx[(2 * 8 + q) * 1024 + t];
                DOT8(hr0, wr, yv) DOT8(hz0, wz, yv) DOT8(hn0, wn, yv)
            }
            {
                h8 yv = *(const h8*)(yh + p2 * 8 + (q + 1) * 32);
                h8 wr = WHx[(0 * 8 + q + 1) * 1024 + t];
                h8 wz = WHx[(1 * 8 + q + 1) * 1024 + t];
                h8 wn = WHx[(2 * 8 + q + 1) * 1024 + t];
                DOT8(hr1, wr, yv) DOT8(hz1, wz, yv) DOT8(hn1, wn, yv)
            }
        }
        float Rp = dppadd<0x4E>(dppadd<0xB1>(xr + hr0 + hr1));
        float Zp = dppadd<0x4E>(dppadd<0xB1>(xz + hz0 + hz1));
        float Ip = dppadd<0x4E>(dppadd<0xB1>(xn));
        float Hp = dppadd<0x4E>(dppadd<0xB1>(hn0 + hn1));
        float r_g = fast_sigmoid(Rp + bihr + bhhr);
        float z_g = fast_sigmoid(Zp + bihz + bhhz);
        float n_g = fast_tanh(Ip + bihn + r_g * (Hp + bhhn));
        h = n_g + z_g * (h - n_g);
        __syncthreads();   // all yh reads done before drift overwrites yh

        // ---- ODE integrate: single dopri5 step over the whole interval ----
        const float t0v = tvec[s];
        const float t1v = (s > 0) ? tvec[s - 1] : tvec[0];
        const float dt  = (t1v - t0v);

        if (dt != 0.0f) {   // block-uniform; dt==0 only at s==0 (exact skip)
            float k1, k2, k3, k4, k5, k6;
            DRIFT(h, k1);
            DRIFT(fmaf(dt * 0.2f, k1, h), k2);
            DRIFT(h + dt * (0.075f * k1 + 0.225f * k2), k3);
            DRIFT(h + dt * ((44.0f/45.0f) * k1 + (-56.0f/15.0f) * k2
                          + (32.0f/9.0f)  * k3), k4);
            DRIFT(h + dt * ((19372.0f/6561.0f) * k1 + (-25360.0f/2187.0f) * k2
                          + (64448.0f/6561.0f) * k3 + (-212.0f/729.0f)   * k4), k5);
            DRIFT(h + dt * ((9017.0f/3168.0f)  * k1 + (-355.0f/33.0f)    * k2
                          + (46732.0f/5247.0f) * k3 + (49.0f/176.0f)     * k4
                          + (-5103.0f/18656.0f)* k5), k6);
            h = h + dt * ((35.0f/384.0f)    * k1 + (500.0f/1113.0f)  * k3
                        + (125.0f/192.0f)   * k4 + (-2187.0f/6784.0f) * k5
                        + (11.0f/84.0f)     * k6);
        }

        if (p2 == 0) out[((size_t)s * BATCH + b) * HDIM + j] = h;
        __syncthreads();   // protect next step's xh/yh writes
    }
}

extern "C" void kernel_launch(void* const* d_in, const int* in_sizes, int n_in,
                              void* d_out, int out_size, void* d_ws, size_t ws_size,
                              hipStream_t stream) {
    const float* x    = (const float*)d_in[0];
    const float* tvec = (const float*)d_in[1];
    const float* W_ih = (const float*)d_in[2];
    const float* W_hh = (const float*)d_in[3];
    const float* b_ih = (const float*)d_in[4];
    const float* b_hh = (const float*)d_in[5];
    const float* W1   = (const float*)d_in[6];
    const float* b1   = (const float*)d_in[7];
    const float* W2   = (const float*)d_in[8];
    const float* b2   = (const float*)d_in[9];
    float* out = (float*)d_out;

    h8* WHx = (h8*)d_ws;                                   // 24576*16 = 393216 B
    h8* WIx = (h8*)((char*)d_ws + 24576 * 16);             //  6144*16 =  98304 B

    hipLaunchKernelGGL(prep_kernel, dim3(120), dim3(256), 0, stream,
                       W_ih, W_hh, WHx, WIx);
    hipLaunchKernelGGL(odegru_kernel, dim3(BATCH), dim3(1024), 0, stream,
                       x, tvec, b_ih, b_hh, W1, b1, W2, b2, WHx, WIx, out);
}